// Round 10
// baseline (248.149 us; speedup 1.0000x reference)
//
#include <hip/hip_runtime.h>
#include <math.h>

// Causal SDPA, B=4 H=8 S=2048 D=64, scale = 1/sqrt(512)  (HIDDEN_SIZE=512).
// d_out (fp32): [B,H,S,D] output O followed by [B,H,S,S] attn probs P.
// Inputs fp32. mask input ignored (statically causal, triu k=1).
//
// R10: BARRIER-FREE main kernel. Transcode writes bf16 K (row-major) and
// bf16 V^T (column-major) to d_ws; K/V MFMA fragments are direct 16B global
// loads -> no LDS staging, zero __syncthreads, waves fully independent.
// Complementary qt2 pairing balances per-CU work (68 tile-iters each).

#define S_LEN 2048
#define SCALE 0.04419417382415922f  // 1/sqrt(512)
#define NELEM 4194304               // 4*8*2048*64 per tensor

typedef __attribute__((ext_vector_type(8))) short bf16x8;
typedef __attribute__((ext_vector_type(4))) short bf16x4;
typedef __attribute__((ext_vector_type(4))) float f32x4;

__device__ __forceinline__ short f2bf(float f) {
  unsigned u = __builtin_bit_cast(unsigned, f);
  u = (u + 0x7FFFu + ((u >> 16) & 1u)) >> 16;
  return (short)u;
}

__device__ __forceinline__ bf16x8 pack8(float4 a, float4 b) {
  bf16x8 t;
  t[0] = f2bf(a.x); t[1] = f2bf(a.y); t[2] = f2bf(a.z); t[3] = f2bf(a.w);
  t[4] = f2bf(b.x); t[5] = f2bf(b.y); t[6] = f2bf(b.z); t[7] = f2bf(b.w);
  return t;
}

__device__ __forceinline__ void nt_store4(float* p, float x, float y, float z2, float w2) {
  f32x4 v; v[0] = x; v[1] = y; v[2] = z2; v[3] = w2;
  __builtin_nontemporal_store(v, (f32x4*)p);
}

// ---- prep: K -> bf16 row-major, V -> bf16 TRANSPOSED ([bh][d][k]) ----
__global__ __launch_bounds__(256)
void transcode_kernel(const float* K, const float* V, short* Kw, short* Vwt) {
  __shared__ __align__(16) short tile[64][72];   // V tile, bf16
  const int bh = blockIdx.x >> 5;
  const int kt = blockIdx.x & 31;
  const int r  = threadIdx.x >> 2;          // 0..63
  const int c0 = (threadIdx.x & 3) << 4;    // 0,16,32,48

  const size_t base = ((size_t)(bh * S_LEN + (kt << 6) + r)) * 64 + c0;
  {
    const float4* k4 = (const float4*)(K + base);
    *(bf16x8*)(Kw + base)     = pack8(k4[0], k4[1]);
    *(bf16x8*)(Kw + base + 8) = pack8(k4[2], k4[3]);
    const float4* v4 = (const float4*)(V + base);
    *(bf16x8*)&tile[r][c0]     = pack8(v4[0], v4[1]);
    *(bf16x8*)&tile[r][c0 + 8] = pack8(v4[2], v4[3]);
  }
  __syncthreads();
  {
    const int d   = threadIdx.x >> 2;       // 0..63 (V^T row)
    const int kc0 = (threadIdx.x & 3) << 4; // 0,16,32,48
    bf16x8 o0, o1;
#pragma unroll
    for (int j = 0; j < 8; ++j) o0[j] = tile[kc0 + j][d];
#pragma unroll
    for (int j = 0; j < 8; ++j) o1[j] = tile[kc0 + 8 + j][d];
    short* dst = Vwt + ((size_t)(bh * 64 + d)) * S_LEN + (kt << 6) + kc0;
    *(bf16x8*)dst       = o0;
    *(bf16x8*)(dst + 8) = o1;
  }
}

// ================= barrier-free SDPA (bf16 K + V^T in d_ws) =================
__global__ __launch_bounds__(512, 4)
void sdpa_kernel(const float* Q, const short* Kw, const short* Vwt,
                 float* outO, float* outP)
{
  __shared__ __align__(16) short ldsP[8][16][72];   // per-wave P tile [q][k]

  const int tid  = threadIdx.x;
  const int lane = tid & 63;
  const int w    = tid >> 6;     // 8 waves
  const int lrow = lane & 15;
  const int lgrp = lane >> 4;

  // complementary pairing: CU's blocks (b, b+256) get qt2 summing to 15
  const int idx = blockIdx.x >> 5;
  const int bh  = blockIdx.x & 31;
  const int qt2 = (idx < 8) ? (15 - idx) : (idx - 8);
  const int q0  = qt2 << 7;            // 128 q-rows per block
  const int NT  = 2 * qt2 + 2;         // kt tiles covered (cols < NT*64)
  const int qrow = q0 + (w << 4) + lrow;
  const int wmin = q0 + (w << 4);
  const int wmax = wmin + 15;

  const short* Kb = Kw  + (size_t)bh * S_LEN * 64;   // [k][d] bf16
  const short* Vb = Vwt + (size_t)bh * 64 * S_LEN;   // [d][k] bf16

  // K fragment for S^T=K*Q^T: lane = A[row=nt*16+lrow][k=ks*32+lgrp*8..+7]
#define QKT(accv, kt)                                                         \
  _Pragma("unroll")                                                           \
  for (int nt = 0; nt < 4; ++nt) {                                            \
    f32x4 a_ = {0.f, 0.f, 0.f, 0.f};                                          \
    _Pragma("unroll")                                                         \
    for (int ks = 0; ks < 2; ++ks) {                                          \
      bf16x8 kf_ = *(const bf16x8*)(Kb +                                      \
          ((size_t)(((kt) << 6) + nt * 16 + lrow)) * 64 + ks * 32 + lgrp * 8);\
      a_ = __builtin_amdgcn_mfma_f32_16x16x32_bf16(kf_, qf[ks], a_, 0, 0, 0); \
    }                                                                         \
    accv[nt] = a_;                                                            \
  }

  // mask needed iff tile max-col > wave MIN row
#define MASKSCALE(accv, kt)                                                   \
  if ((((kt) << 6) + 63) > wmin) {                                            \
    _Pragma("unroll")                                                         \
    for (int nt = 0; nt < 4; ++nt)                                            \
      _Pragma("unroll")                                                       \
      for (int rg = 0; rg < 4; ++rg) {                                        \
        const int col = ((kt) << 6) + nt * 16 + (lgrp << 2) + rg;             \
        accv[nt][rg] = (col > qrow) ? -INFINITY : accv[nt][rg] * SCALE;       \
      }                                                                       \
  } else {                                                                    \
    _Pragma("unroll")                                                         \
    for (int nt = 0; nt < 4; ++nt)                                            \
      _Pragma("unroll")                                                       \
      for (int rg = 0; rg < 4; ++rg) accv[nt][rg] *= SCALE;                   \
  }

  // Q fragment (B operand): lane holds Q[qrow][ks*32+lgrp*8..+7]
  bf16x8 qf[2];
  {
    const float* qb = Q + ((size_t)(bh * S_LEN + qrow)) * 64;
#pragma unroll
    for (int ks = 0; ks < 2; ++ks) {
      const float* p = qb + ks * 32 + lgrp * 8;
      qf[ks] = pack8(*(const float4*)p, *(const float4*)(p + 4));
    }
  }

  float m_run = -INFINITY;
  float l_run = 0.f;

  // ============ pass 1: exact row max + denominator (no LDS, no barriers) ==
  const int kt_end = wmax >> 6;   // last tile with any unmasked col
  for (int kt = 0; kt <= kt_end; ++kt) {
    f32x4 acc[4];
    QKT(acc, kt)
    MASKSCALE(acc, kt)

    float tm = -INFINITY;
#pragma unroll
    for (int nt = 0; nt < 4; ++nt)
#pragma unroll
      for (int rg = 0; rg < 4; ++rg) tm = fmaxf(tm, acc[nt][rg]);
    tm = fmaxf(tm, __shfl_xor(tm, 16));
    tm = fmaxf(tm, __shfl_xor(tm, 32));
    const float nm = fmaxf(m_run, tm);

    float ps = 0.f;
#pragma unroll
    for (int nt = 0; nt < 4; ++nt)
#pragma unroll
      for (int rg = 0; rg < 4; ++rg) ps += __expf(acc[nt][rg] - nm);
    ps += __shfl_xor(ps, 16);
    ps += __shfl_xor(ps, 32);

    l_run = l_run * __expf(m_run - nm) + ps;
    m_run = nm;
  }

  const float inv_l = 1.f / l_run;

  f32x4 oacc[4];
#pragma unroll
  for (int nt = 0; nt < 4; ++nt) oacc[nt] = (f32x4){0.f, 0.f, 0.f, 0.f};

  const size_t pbase = (size_t)bh * S_LEN * S_LEN + (size_t)qrow * S_LEN;

  // ============ pass 2: probs, attn store, PV (no barriers) ============
  for (int kt = 0; kt < NT; ++kt) {
    if ((kt << 6) > wmax) {
      // fully-masked tile for this wave: probabilities are exactly zero
#pragma unroll
      for (int nt = 0; nt < 4; ++nt)
        nt_store4(outP + pbase + (kt << 6) + nt * 16 + (lgrp << 2),
                  0.f, 0.f, 0.f, 0.f);
      continue;
    }

    f32x4 acc[4];
    QKT(acc, kt)
    MASKSCALE(acc, kt)

    // probabilities: NT float4 global store + b64 LDS store per nt
#pragma unroll
    for (int nt = 0; nt < 4; ++nt) {
      float p0 = __expf(acc[nt][0] - m_run) * inv_l;
      float p1 = __expf(acc[nt][1] - m_run) * inv_l;
      float p2 = __expf(acc[nt][2] - m_run) * inv_l;
      float p3 = __expf(acc[nt][3] - m_run) * inv_l;
      nt_store4(outP + pbase + (kt << 6) + nt * 16 + (lgrp << 2), p0, p1, p2, p3);
      bf16x4 pb;
      pb[0] = f2bf(p0); pb[1] = f2bf(p1);
      pb[2] = f2bf(p2); pb[3] = f2bf(p3);
      *(bf16x4*)&ldsP[w][lrow][nt * 16 + (lgrp << 2)] = pb;
    }

    // PV: A = own-wave P tile (16q x 64k), B = V^T fragments from global.
    // ldsP[w] is wave-private: same-wave write->read ordered by lgkmcnt.
#pragma unroll
    for (int nt = 0; nt < 4; ++nt) {
#pragma unroll
      for (int ks = 0; ks < 2; ++ks) {
        bf16x8 pa = *(const bf16x8*)&ldsP[w][lrow][ks * 32 + lgrp * 8];
        bf16x8 vb = *(const bf16x8*)(Vb +
            ((size_t)(nt * 16 + lrow)) * S_LEN + (kt << 6) + ks * 32 + lgrp * 8);
        oacc[nt] = __builtin_amdgcn_mfma_f32_16x16x32_bf16(pa, vb, oacc[nt], 0, 0, 0);
      }
    }
  }

  // ---- zero the strictly-masked column range (cols >= NT*64) ----
  {
    const int kz = NT << 6;
    if (kz < S_LEN) {
      for (int row = 0; row < 128; ++row) {
        const size_t base = (size_t)bh * S_LEN * S_LEN + (size_t)(q0 + row) * S_LEN;
        for (int c = kz + (tid << 2); c < S_LEN; c += 512 * 4) {
          nt_store4(outP + base + c, 0.f, 0.f, 0.f, 0.f);
        }
      }
    }
  }

  // ---- write O (fp32): O row = q0+16w+4*lgrp+rg, col d = nt*16+lrow ----
#pragma unroll
  for (int nt = 0; nt < 4; ++nt) {
#pragma unroll
    for (int rg = 0; rg < 4; ++rg) {
      const int rl = (lgrp << 2) + rg;
      const int d  = nt * 16 + lrow;
      __builtin_nontemporal_store(
          oacc[nt][rg],
          outO + ((size_t)(bh * S_LEN + q0 + (w << 4) + rl)) * 64 + d);
    }
  }
}

// ================= fallback (fp32 K/V via LDS; R9-proven) =================
__global__ __launch_bounds__(512, 4)
void sdpa_fallback(const float* Q, const float* K, const float* V,
                   float* outO, float* outP)
{
  __shared__ __align__(16) short ldsK[64][72];
  __shared__ __align__(16) short ldsV[64][72];
  __shared__ __align__(16) short ldsP[8][16][72];

  const int tid  = threadIdx.x;
  const int lane = tid & 63;
  const int w    = tid >> 6;
  const int lrow = lane & 15;
  const int lgrp = lane >> 4;

  const int qt2 = 15 - (blockIdx.x >> 5);
  const int bh  = blockIdx.x & 31;
  const int q0  = qt2 << 7;
  const int NT  = 2 * qt2 + 2;
  const int qrow = q0 + (w << 4) + lrow;
  const int wmin = q0 + (w << 4);
  const int wmax = wmin + 15;

  const int sr = tid >> 3;
  const int c8 = (tid & 7) << 3;

#define FSTAGEK(kt) {                                                         \
    const float* s_ = K + ((size_t)(bh * S_LEN + ((kt) << 6) + sr)) * 64 + c8;\
    *(bf16x8*)&ldsK[sr][c8] = pack8(((const float4*)s_)[0],                   \
                                    ((const float4*)s_)[1]); }
#define FSTAGEV(kt) {                                                         \
    const float* s_ = V + ((size_t)(bh * S_LEN + ((kt) << 6) + sr)) * 64 + c8;\
    bf16x8 vv_ = pack8(((const float4*)s_)[0], ((const float4*)s_)[1]);       \
    _Pragma("unroll")                                                         \
    for (int j_ = 0; j_ < 8; ++j_) ldsV[c8 + j_][sr] = vv_[j_]; }
#define FQKT(accv)                                                            \
  _Pragma("unroll")                                                           \
  for (int nt = 0; nt < 4; ++nt) {                                            \
    f32x4 a_ = {0.f, 0.f, 0.f, 0.f};                                          \
    _Pragma("unroll")                                                         \
    for (int ks = 0; ks < 2; ++ks) {                                          \
      bf16x8 kf_ = *(const bf16x8*)&ldsK[nt * 16 + lrow][ks * 32 + lgrp * 8]; \
      a_ = __builtin_amdgcn_mfma_f32_16x16x32_bf16(kf_, qf[ks], a_, 0, 0, 0); \
    }                                                                         \
    accv[nt] = a_;                                                            \
  }

  bf16x8 qf[2];
  {
    const float* qb = Q + ((size_t)(bh * S_LEN + qrow)) * 64;
#pragma unroll
    for (int ks = 0; ks < 2; ++ks) {
      const float* p = qb + ks * 32 + lgrp * 8;
      qf[ks] = pack8(*(const float4*)p, *(const float4*)(p + 4));
    }
  }

  float m_run = -INFINITY;
  float l_run = 0.f;

  for (int kt = 0; kt < NT; ++kt) {
    __syncthreads();
    FSTAGEK(kt)
    __syncthreads();
    if ((kt << 6) > wmax) continue;

    f32x4 acc[4];
    FQKT(acc)
    MASKSCALE(acc, kt)

    float tm = -INFINITY;
#pragma unroll
    for (int nt = 0; nt < 4; ++nt)
#pragma unroll
      for (int rg = 0; rg < 4; ++rg) tm = fmaxf(tm, acc[nt][rg]);
    tm = fmaxf(tm, __shfl_xor(tm, 16));
    tm = fmaxf(tm, __shfl_xor(tm, 32));
    const float nm = fmaxf(m_run, tm);

    float ps = 0.f;
#pragma unroll
    for (int nt = 0; nt < 4; ++nt)
#pragma unroll
      for (int rg = 0; rg < 4; ++rg) ps += __expf(acc[nt][rg] - nm);
    ps += __shfl_xor(ps, 16);
    ps += __shfl_xor(ps, 32);

    l_run = l_run * __expf(m_run - nm) + ps;
    m_run = nm;
  }

  const float inv_l = 1.f / l_run;

  f32x4 oacc[4];
#pragma unroll
  for (int nt = 0; nt < 4; ++nt) oacc[nt] = (f32x4){0.f, 0.f, 0.f, 0.f};

  const size_t pbase = (size_t)bh * S_LEN * S_LEN + (size_t)qrow * S_LEN;

  for (int kt = 0; kt < NT; ++kt) {
    __syncthreads();
    FSTAGEK(kt)
    FSTAGEV(kt)
    __syncthreads();

    if ((kt << 6) > wmax) {
#pragma unroll
      for (int nt = 0; nt < 4; ++nt)
        nt_store4(outP + pbase + (kt << 6) + nt * 16 + (lgrp << 2),
                  0.f, 0.f, 0.f, 0.f);
      continue;
    }

    f32x4 acc[4];
    FQKT(acc)
    MASKSCALE(acc, kt)

#pragma unroll
    for (int nt = 0; nt < 4; ++nt) {
      float p0 = __expf(acc[nt][0] - m_run) * inv_l;
      float p1 = __expf(acc[nt][1] - m_run) * inv_l;
      float p2 = __expf(acc[nt][2] - m_run) * inv_l;
      float p3 = __expf(acc[nt][3] - m_run) * inv_l;
      nt_store4(outP + pbase + (kt << 6) + nt * 16 + (lgrp << 2), p0, p1, p2, p3);
      bf16x4 pb;
      pb[0] = f2bf(p0); pb[1] = f2bf(p1);
      pb[2] = f2bf(p2); pb[3] = f2bf(p3);
      *(bf16x4*)&ldsP[w][lrow][nt * 16 + (lgrp << 2)] = pb;
    }

#pragma unroll
    for (int nt = 0; nt < 4; ++nt) {
#pragma unroll
      for (int ks = 0; ks < 2; ++ks) {
        bf16x8 pa = *(const bf16x8*)&ldsP[w][lrow][ks * 32 + lgrp * 8];
        bf16x8 vb = *(const bf16x8*)&ldsV[nt * 16 + lrow][ks * 32 + lgrp * 8];
        oacc[nt] = __builtin_amdgcn_mfma_f32_16x16x32_bf16(pa, vb, oacc[nt], 0, 0, 0);
      }
    }
  }

  {
    const int kz = NT << 6;
    if (kz < S_LEN) {
      for (int row = 0; row < 128; ++row) {
        const size_t base = (size_t)bh * S_LEN * S_LEN + (size_t)(q0 + row) * S_LEN;
        for (int c = kz + (tid << 2); c < S_LEN; c += 512 * 4) {
          nt_store4(outP + base + c, 0.f, 0.f, 0.f, 0.f);
        }
      }
    }
  }

#pragma unroll
  for (int nt = 0; nt < 4; ++nt) {
#pragma unroll
    for (int rg = 0; rg < 4; ++rg) {
      const int rl = (lgrp << 2) + rg;
      const int d  = nt * 16 + lrow;
      __builtin_nontemporal_store(
          oacc[nt][rg],
          outO + ((size_t)(bh * S_LEN + q0 + (w << 4) + rl)) * 64 + d);
    }
  }
}

extern "C" void kernel_launch(void* const* d_in, const int* in_sizes, int n_in,
                              void* d_out, int out_size, void* d_ws, size_t ws_size,
                              hipStream_t stream) {
  const float* Q = (const float*)d_in[0];
  const float* K = (const float*)d_in[1];
  const float* V = (const float*)d_in[2];
  // d_in[3] (mask) is statically causal -> not read.
  float* outO = (float*)d_out;
  float* outP = outO + (size_t)32 * S_LEN * 64;  // after [B,H,S,D] output

  const size_t need = (size_t)2 * NELEM * sizeof(short);  // 16.8 MB
  if (ws_size >= need) {
    short* Kw  = (short*)d_ws;
    short* Vwt = Kw + NELEM;
    transcode_kernel<<<dim3(1024), dim3(256), 0, stream>>>(K, V, Kw, Vwt);
    sdpa_kernel<<<dim3(512), dim3(512), 0, stream>>>(Q, Kw, Vwt, outO, outP);
  } else {
    sdpa_fallback<<<dim3(512), dim3(512), 0, stream>>>(Q, K, V, outO, outP);
  }
}

// Round 12
// 238.389 us; speedup vs baseline: 1.0409x; 1.0409x over previous
//
#include <hip/hip_runtime.h>
#include <math.h>

// Causal SDPA, B=4 H=8 S=2048 D=64, scale = 1/sqrt(512)  (HIDDEN_SIZE=512).
// d_out (fp32): [B,H,S,D] output O followed by [B,H,S,S] attn probs P.
// Inputs fp32. mask input ignored (statically causal, triu k=1).
//
// R12: contiguous P stores, barrier-ordered. Per kt-tile each wave transposes
// its 16x64 fp32 P tile through LDS (all-lane writes, __syncthreads, reads):
// each store instruction = 4 rows x 256 B contiguous (full 128B lines).
// QKT/PV read bf16 K / V^T transcoded into d_ws (barrier-free, from R10).

#define S_LEN 2048
#define SCALE 0.04419417382415922f  // 1/sqrt(512)
#define NELEM 4194304               // 4*8*2048*64 per tensor

typedef __attribute__((ext_vector_type(8))) short bf16x8;
typedef __attribute__((ext_vector_type(4))) short bf16x4;
typedef __attribute__((ext_vector_type(4))) float f32x4;

__device__ __forceinline__ short f2bf(float f) {
  unsigned u = __builtin_bit_cast(unsigned, f);
  u = (u + 0x7FFFu + ((u >> 16) & 1u)) >> 16;
  return (short)u;
}

__device__ __forceinline__ bf16x8 pack8(float4 a, float4 b) {
  bf16x8 t;
  t[0] = f2bf(a.x); t[1] = f2bf(a.y); t[2] = f2bf(a.z); t[3] = f2bf(a.w);
  t[4] = f2bf(b.x); t[5] = f2bf(b.y); t[6] = f2bf(b.z); t[7] = f2bf(b.w);
  return t;
}

__device__ __forceinline__ void nt_store4(float* p, float x, float y, float z2, float w2) {
  f32x4 v; v[0] = x; v[1] = y; v[2] = z2; v[3] = w2;
  __builtin_nontemporal_store(v, (f32x4*)p);
}

// ---- prep: K -> bf16 row-major, V -> bf16 TRANSPOSED ([bh][d][k]) ----
__global__ __launch_bounds__(256)
void transcode_kernel(const float* K, const float* V, short* Kw, short* Vwt) {
  __shared__ __align__(16) short tile[64][72];   // V tile, bf16
  const int bh = blockIdx.x >> 5;
  const int kt = blockIdx.x & 31;
  const int r  = threadIdx.x >> 2;          // 0..63
  const int c0 = (threadIdx.x & 3) << 4;    // 0,16,32,48

  const size_t base = ((size_t)(bh * S_LEN + (kt << 6) + r)) * 64 + c0;
  {
    const float4* k4 = (const float4*)(K + base);
    *(bf16x8*)(Kw + base)     = pack8(k4[0], k4[1]);
    *(bf16x8*)(Kw + base + 8) = pack8(k4[2], k4[3]);
    const float4* v4 = (const float4*)(V + base);
    *(bf16x8*)&tile[r][c0]     = pack8(v4[0], v4[1]);
    *(bf16x8*)&tile[r][c0 + 8] = pack8(v4[2], v4[3]);
  }
  __syncthreads();
  {
    const int d   = threadIdx.x >> 2;       // 0..63 (V^T row)
    const int kc0 = (threadIdx.x & 3) << 4; // 0,16,32,48
    bf16x8 o0, o1;
#pragma unroll
    for (int j = 0; j < 8; ++j) o0[j] = tile[kc0 + j][d];
#pragma unroll
    for (int j = 0; j < 8; ++j) o1[j] = tile[kc0 + 8 + j][d];
    short* dst = Vwt + ((size_t)(bh * 64 + d)) * S_LEN + (kt << 6) + kc0;
    *(bf16x8*)dst       = o0;
    *(bf16x8*)(dst + 8) = o1;
  }
}

// ================= SDPA (bf16 K + V^T in d_ws) =================
__global__ __launch_bounds__(512, 3)
void sdpa_kernel(const float* Q, const short* Kw, const short* Vwt,
                 float* outO, float* outP)
{
  __shared__ __align__(16) short ldsP[8][16][72];   // per-wave P bf16 [q][k]
  __shared__ __align__(16) float ldsT[8][16][68];   // per-wave fp32 transpose

  const int tid  = threadIdx.x;
  const int lane = tid & 63;
  const int w    = tid >> 6;     // 8 waves
  const int lrow = lane & 15;
  const int lgrp = lane >> 4;

  // complementary pairing: blocks (idx, idx+8) get qt2 summing to 15
  const int idx = blockIdx.x >> 5;
  const int bh  = blockIdx.x & 31;
  const int qt2 = (idx < 8) ? (15 - idx) : (idx - 8);
  const int q0  = qt2 << 7;            // 128 q-rows per block
  const int NT  = 2 * qt2 + 2;         // kt tiles covered (cols < NT*64)
  const int qrow = q0 + (w << 4) + lrow;
  const int wmin = q0 + (w << 4);
  const int wmax = wmin + 15;

  const short* Kb = Kw  + (size_t)bh * S_LEN * 64;   // [k][d] bf16
  const short* Vb = Vwt + (size_t)bh * 64 * S_LEN;   // [d][k] bf16

#define QKT(accv, kt)                                                         \
  _Pragma("unroll")                                                           \
  for (int nt = 0; nt < 4; ++nt) {                                            \
    f32x4 a_ = {0.f, 0.f, 0.f, 0.f};                                          \
    _Pragma("unroll")                                                         \
    for (int ks = 0; ks < 2; ++ks) {                                          \
      bf16x8 kf_ = *(const bf16x8*)(Kb +                                      \
          ((size_t)(((kt) << 6) + nt * 16 + lrow)) * 64 + ks * 32 + lgrp * 8);\
      a_ = __builtin_amdgcn_mfma_f32_16x16x32_bf16(kf_, qf[ks], a_, 0, 0, 0); \
    }                                                                         \
    accv[nt] = a_;                                                            \
  }

  // mask needed iff tile max-col > wave MIN row
#define MASKSCALE(accv, kt)                                                   \
  if ((((kt) << 6) + 63) > wmin) {                                            \
    _Pragma("unroll")                                                         \
    for (int nt = 0; nt < 4; ++nt)                                            \
      _Pragma("unroll")                                                       \
      for (int rg = 0; rg < 4; ++rg) {                                        \
        const int col = ((kt) << 6) + nt * 16 + (lgrp << 2) + rg;             \
        accv[nt][rg] = (col > qrow) ? -INFINITY : accv[nt][rg] * SCALE;       \
      }                                                                       \
  } else {                                                                    \
    _Pragma("unroll")                                                         \
    for (int nt = 0; nt < 4; ++nt)                                            \
      _Pragma("unroll")                                                       \
      for (int rg = 0; rg < 4; ++rg) accv[nt][rg] *= SCALE;                   \
  }

  // Q fragment (B operand): lane holds Q[qrow][ks*32+lgrp*8..+7]
  bf16x8 qf[2];
  {
    const float* qb = Q + ((size_t)(bh * S_LEN + qrow)) * 64;
#pragma unroll
    for (int ks = 0; ks < 2; ++ks) {
      const float* p = qb + ks * 32 + lgrp * 8;
      qf[ks] = pack8(*(const float4*)p, *(const float4*)(p + 4));
    }
  }

  float m_run = -INFINITY;
  float l_run = 0.f;

  // ============ pass 1: exact row max + denominator (no barriers) ==========
  const int kt_end = wmax >> 6;
  for (int kt = 0; kt <= kt_end; ++kt) {
    f32x4 acc[4];
    QKT(acc, kt)
    MASKSCALE(acc, kt)

    float tm = -INFINITY;
#pragma unroll
    for (int nt = 0; nt < 4; ++nt)
#pragma unroll
      for (int rg = 0; rg < 4; ++rg) tm = fmaxf(tm, acc[nt][rg]);
    tm = fmaxf(tm, __shfl_xor(tm, 16));
    tm = fmaxf(tm, __shfl_xor(tm, 32));
    const float nm = fmaxf(m_run, tm);

    float ps = 0.f;
#pragma unroll
    for (int nt = 0; nt < 4; ++nt)
#pragma unroll
      for (int rg = 0; rg < 4; ++rg) ps += __expf(acc[nt][rg] - nm);
    ps += __shfl_xor(ps, 16);
    ps += __shfl_xor(ps, 32);

    l_run = l_run * __expf(m_run - nm) + ps;
    m_run = nm;
  }

  const float inv_l = 1.f / l_run;

  f32x4 oacc[4];
#pragma unroll
  for (int nt = 0; nt < 4; ++nt) oacc[nt] = (f32x4){0.f, 0.f, 0.f, 0.f};

  const size_t pOutBase = (size_t)bh * S_LEN * S_LEN;

  // ===== pass 2 (uniform trip count; 2 barriers/tile, no skipping) =====
  for (int kt = 0; kt < NT; ++kt) {
    f32x4 pr[4];
    if ((kt << 6) <= wmax) {   // wave has live columns in this tile
      f32x4 acc[4];
      QKT(acc, kt)
      MASKSCALE(acc, kt)
#pragma unroll
      for (int nt = 0; nt < 4; ++nt) {
        pr[nt][0] = __expf(acc[nt][0] - m_run) * inv_l;
        pr[nt][1] = __expf(acc[nt][1] - m_run) * inv_l;
        pr[nt][2] = __expf(acc[nt][2] - m_run) * inv_l;
        pr[nt][3] = __expf(acc[nt][3] - m_run) * inv_l;
        bf16x4 pb;
        pb[0] = f2bf(pr[nt][0]); pb[1] = f2bf(pr[nt][1]);
        pb[2] = f2bf(pr[nt][2]); pb[3] = f2bf(pr[nt][3]);
        *(bf16x4*)&ldsP[w][lrow][nt * 16 + (lgrp << 2)] = pb;
      }
      // PV (wave-private ldsP write->read; passed R3-R10)
#pragma unroll
      for (int nt = 0; nt < 4; ++nt) {
#pragma unroll
        for (int ks = 0; ks < 2; ++ks) {
          bf16x8 pa = *(const bf16x8*)&ldsP[w][lrow][ks * 32 + lgrp * 8];
          bf16x8 vb = *(const bf16x8*)(Vb +
              ((size_t)(nt * 16 + lrow)) * S_LEN + (kt << 6) + ks * 32 + lgrp * 8);
          oacc[nt] = __builtin_amdgcn_mfma_f32_16x16x32_bf16(pa, vb, oacc[nt], 0, 0, 0);
        }
      }
    } else {
#pragma unroll
      for (int nt = 0; nt < 4; ++nt) pr[nt] = (f32x4){0.f, 0.f, 0.f, 0.f};
    }

    // ---- transposed contiguous store (barrier-ordered) ----
    // write: lane (lrow,lgrp) owns row lrow, cols nt*16+lgrp*4..+3
#pragma unroll
    for (int nt = 0; nt < 4; ++nt)
      *(f32x4*)&ldsT[w][lrow][nt * 16 + (lgrp << 2)] = pr[nt];
    __syncthreads();
    // read: instruction j stores rows j*4+lgrp (4 rows x 256 B contiguous)
#pragma unroll
    for (int j = 0; j < 4; ++j) {
      const int r = (j << 2) + lgrp;
      f32x4 v = *(const f32x4*)&ldsT[w][r][lrow << 2];
      const int grow = q0 + (w << 4) + r;
      __builtin_nontemporal_store(v, (f32x4*)(outP + pOutBase
          + (size_t)grow * S_LEN + (kt << 6) + (lrow << 2)));
    }
    __syncthreads();   // WAR: next tile's writes
  }

  // ---- zero the strictly-masked column range (cols >= NT*64) ----
  {
    const int kz = NT << 6;
    if (kz < S_LEN) {
      for (int row = 0; row < 128; ++row) {
        const size_t base = pOutBase + (size_t)(q0 + row) * S_LEN;
        for (int c = kz + (tid << 2); c < S_LEN; c += 512 * 4) {
          nt_store4(outP + base + c, 0.f, 0.f, 0.f, 0.f);
        }
      }
    }
  }

  // ---- write O (fp32): O row = q0+16w+4*lgrp+rg, col d = nt*16+lrow ----
#pragma unroll
  for (int nt = 0; nt < 4; ++nt) {
#pragma unroll
    for (int rg = 0; rg < 4; ++rg) {
      const int rl = (lgrp << 2) + rg;
      const int d  = nt * 16 + lrow;
      __builtin_nontemporal_store(
          oacc[nt][rg],
          outO + ((size_t)(bh * S_LEN + q0 + (w << 4) + rl)) * 64 + d);
    }
  }
}

// ================= fallback (fp32 K/V via LDS; R9-proven) =================
__global__ __launch_bounds__(512, 4)
void sdpa_fallback(const float* Q, const float* K, const float* V,
                   float* outO, float* outP)
{
  __shared__ __align__(16) short ldsK[64][72];
  __shared__ __align__(16) short ldsV[64][72];
  __shared__ __align__(16) short ldsP[8][16][72];

  const int tid  = threadIdx.x;
  const int lane = tid & 63;
  const int w    = tid >> 6;
  const int lrow = lane & 15;
  const int lgrp = lane >> 4;

  const int qt2 = 15 - (blockIdx.x >> 5);
  const int bh  = blockIdx.x & 31;
  const int q0  = qt2 << 7;
  const int NT  = 2 * qt2 + 2;
  const int qrow = q0 + (w << 4) + lrow;
  const int wmin = q0 + (w << 4);
  const int wmax = wmin + 15;

  const int sr = tid >> 3;
  const int c8 = (tid & 7) << 3;

#define FSTAGEK(kt) {                                                         \
    const float* s_ = K + ((size_t)(bh * S_LEN + ((kt) << 6) + sr)) * 64 + c8;\
    *(bf16x8*)&ldsK[sr][c8] = pack8(((const float4*)s_)[0],                   \
                                    ((const float4*)s_)[1]); }
#define FSTAGEV(kt) {                                                         \
    const float* s_ = V + ((size_t)(bh * S_LEN + ((kt) << 6) + sr)) * 64 + c8;\
    bf16x8 vv_ = pack8(((const float4*)s_)[0], ((const float4*)s_)[1]);       \
    _Pragma("unroll")                                                         \
    for (int j_ = 0; j_ < 8; ++j_) ldsV[c8 + j_][sr] = vv_[j_]; }
#define FQKT(accv)                                                            \
  _Pragma("unroll")                                                           \
  for (int nt = 0; nt < 4; ++nt) {                                            \
    f32x4 a_ = {0.f, 0.f, 0.f, 0.f};                                          \
    _Pragma("unroll")                                                         \
    for (int ks = 0; ks < 2; ++ks) {                                          \
      bf16x8 kf_ = *(const bf16x8*)&ldsK[nt * 16 + lrow][ks * 32 + lgrp * 8]; \
      a_ = __builtin_amdgcn_mfma_f32_16x16x32_bf16(kf_, qf[ks], a_, 0, 0, 0); \
    }                                                                         \
    accv[nt] = a_;                                                            \
  }

  bf16x8 qf[2];
  {
    const float* qb = Q + ((size_t)(bh * S_LEN + qrow)) * 64;
#pragma unroll
    for (int ks = 0; ks < 2; ++ks) {
      const float* p = qb + ks * 32 + lgrp * 8;
      qf[ks] = pack8(*(const float4*)p, *(const float4*)(p + 4));
    }
  }

  float m_run = -INFINITY;
  float l_run = 0.f;

  for (int kt = 0; kt < NT; ++kt) {
    __syncthreads();
    FSTAGEK(kt)
    __syncthreads();
    if ((kt << 6) > wmax) continue;

    f32x4 acc[4];
    FQKT(acc)
    MASKSCALE(acc, kt)

    float tm = -INFINITY;
#pragma unroll
    for (int nt = 0; nt < 4; ++nt)
#pragma unroll
      for (int rg = 0; rg < 4; ++rg) tm = fmaxf(tm, acc[nt][rg]);
    tm = fmaxf(tm, __shfl_xor(tm, 16));
    tm = fmaxf(tm, __shfl_xor(tm, 32));
    const float nm = fmaxf(m_run, tm);

    float ps = 0.f;
#pragma unroll
    for (int nt = 0; nt < 4; ++nt)
#pragma unroll
      for (int rg = 0; rg < 4; ++rg) ps += __expf(acc[nt][rg] - nm);
    ps += __shfl_xor(ps, 16);
    ps += __shfl_xor(ps, 32);

    l_run = l_run * __expf(m_run - nm) + ps;
    m_run = nm;
  }

  const float inv_l = 1.f / l_run;

  f32x4 oacc[4];
#pragma unroll
  for (int nt = 0; nt < 4; ++nt) oacc[nt] = (f32x4){0.f, 0.f, 0.f, 0.f};

  const size_t pbase = (size_t)bh * S_LEN * S_LEN + (size_t)qrow * S_LEN;

  for (int kt = 0; kt < NT; ++kt) {
    __syncthreads();
    FSTAGEK(kt)
    FSTAGEV(kt)
    __syncthreads();

    if ((kt << 6) > wmax) {
#pragma unroll
      for (int nt = 0; nt < 4; ++nt)
        nt_store4(outP + pbase + (kt << 6) + nt * 16 + (lgrp << 2),
                  0.f, 0.f, 0.f, 0.f);
      continue;
    }

    f32x4 acc[4];
    FQKT(acc)
    MASKSCALE(acc, kt)

#pragma unroll
    for (int nt = 0; nt < 4; ++nt) {
      float p0 = __expf(acc[nt][0] - m_run) * inv_l;
      float p1 = __expf(acc[nt][1] - m_run) * inv_l;
      float p2 = __expf(acc[nt][2] - m_run) * inv_l;
      float p3 = __expf(acc[nt][3] - m_run) * inv_l;
      nt_store4(outP + pbase + (kt << 6) + nt * 16 + (lgrp << 2), p0, p1, p2, p3);
      bf16x4 pb;
      pb[0] = f2bf(p0); pb[1] = f2bf(p1);
      pb[2] = f2bf(p2); pb[3] = f2bf(p3);
      *(bf16x4*)&ldsP[w][lrow][nt * 16 + (lgrp << 2)] = pb;
    }

#pragma unroll
    for (int nt = 0; nt < 4; ++nt) {
#pragma unroll
      for (int ks = 0; ks < 2; ++ks) {
        bf16x8 pa = *(const bf16x8*)&ldsP[w][lrow][ks * 32 + lgrp * 8];
        bf16x8 vb = *(const bf16x8*)&ldsV[nt * 16 + lrow][ks * 32 + lgrp * 8];
        oacc[nt] = __builtin_amdgcn_mfma_f32_16x16x32_bf16(pa, vb, oacc[nt], 0, 0, 0);
      }
    }
  }

  {
    const int kz = NT << 6;
    if (kz < S_LEN) {
      for (int row = 0; row < 128; ++row) {
        const size_t base = (size_t)bh * S_LEN * S_LEN + (size_t)(q0 + row) * S_LEN;
        for (int c = kz + (tid << 2); c < S_LEN; c += 512 * 4) {
          nt_store4(outP + base + c, 0.f, 0.f, 0.f, 0.f);
        }
      }
    }
  }

#pragma unroll
  for (int nt = 0; nt < 4; ++nt) {
#pragma unroll
    for (int rg = 0; rg < 4; ++rg) {
      const int rl = (lgrp << 2) + rg;
      const int d  = nt * 16 + lrow;
      __builtin_nontemporal_store(
          oacc[nt][rg],
          outO + ((size_t)(bh * S_LEN + q0 + (w << 4) + rl)) * 64 + d);
    }
  }
}

extern "C" void kernel_launch(void* const* d_in, const int* in_sizes, int n_in,
                              void* d_out, int out_size, void* d_ws, size_t ws_size,
                              hipStream_t stream) {
  const float* Q = (const float*)d_in[0];
  const float* K = (const float*)d_in[1];
  const float* V = (const float*)d_in[2];
  // d_in[3] (mask) is statically causal -> not read.
  float* outO = (float*)d_out;
  float* outP = outO + (size_t)32 * S_LEN * 64;  // after [B,H,S,D] output

  const size_t need = (size_t)2 * NELEM * sizeof(short);  // 16.8 MB
  if (ws_size >= need) {
    short* Kw  = (short*)d_ws;
    short* Vwt = Kw + NELEM;
    transcode_kernel<<<dim3(1024), dim3(256), 0, stream>>>(K, V, Kw, Vwt);
    sdpa_kernel<<<dim3(512), dim3(512), 0, stream>>>(Q, Kw, Vwt, outO, outP);
  } else {
    sdpa_fallback<<<dim3(512), dim3(512), 0, stream>>>(Q, K, V, outO, outP);
  }
}

// Round 13
// 207.775 us; speedup vs baseline: 1.1943x; 1.1473x over previous
//
#include <hip/hip_runtime.h>
#include <math.h>

// Causal SDPA, B=4 H=8 S=2048 D=64, scale = 1/sqrt(512)  (HIDDEN_SIZE=512).
// d_out (fp32): [B,H,S,D] output O followed by [B,H,S,S] attn probs P.
// Inputs fp32. mask input ignored (statically causal, triu k=1).
//
// R13 = R7 (best, 214us) + zero-region stores interleaved into pass 1
// (write pipe was idle during the whole read/MFMA-only first pass).
// Swapped QK^T (mfma(K,Q) -> S^T); NT stores; 64-row blocks, 4 waves.

#define S_LEN 2048
#define SCALE 0.04419417382415922f  // 1/sqrt(512)

typedef __attribute__((ext_vector_type(8))) short bf16x8;
typedef __attribute__((ext_vector_type(4))) short bf16x4;
typedef __attribute__((ext_vector_type(4))) float f32x4;

__device__ __forceinline__ short f2bf(float f) {
  unsigned u = __builtin_bit_cast(unsigned, f);
  u = (u + 0x7FFFu + ((u >> 16) & 1u)) >> 16;
  return (short)u;
}

__device__ __forceinline__ bf16x8 pack8(float4 a, float4 b) {
  bf16x8 t;
  t[0] = f2bf(a.x); t[1] = f2bf(a.y); t[2] = f2bf(a.z); t[3] = f2bf(a.w);
  t[4] = f2bf(b.x); t[5] = f2bf(b.y); t[6] = f2bf(b.z); t[7] = f2bf(b.w);
  return t;
}

__device__ __forceinline__ void nt_store4(float* p, float x, float y, float z2, float w2) {
  f32x4 v; v[0] = x; v[1] = y; v[2] = z2; v[3] = w2;
  __builtin_nontemporal_store(v, (f32x4*)p);
}

// LDS rows padded to 72 halfs (144 B): 16B-aligned rows, bank-group rotation.
__global__ __launch_bounds__(256, 2)
void sdpa_kernel(const float* Q, const float* K, const float* V,
                 float* outO, float* outP)
{
  __shared__ __align__(16) short ldsK[64][72];      // K tile   [k][d]
  __shared__ __align__(16) short ldsV[64][72];      // V^T tile [d][k]
  __shared__ __align__(16) short ldsP[4][16][72];   // per-wave P tile [q][k]

  const int tid  = threadIdx.x;
  const int lane = tid & 63;
  const int w    = tid >> 6;
  const int lrow = lane & 15;   // q-row lane index (S^T cols / O d-cols)
  const int lgrp = lane >> 4;

  // heavy q-tiles first: no load-imbalance tail
  const int qt = 31 - (blockIdx.x >> 5);
  const int bh = blockIdx.x & 31;
  const int q0 = qt << 6;
  const int qrow = q0 + (w << 4) + lrow;   // this lane's q row

  // staging map: thread covers tile row sr, 16 floats from col sc
  const int sr = tid & 63;
  const int sc = (tid >> 6) << 4;

  const size_t pOutBase = (size_t)bh * S_LEN * S_LEN;
  const int kz = (qt + 1) << 6;            // first strictly-masked col

  // Q fragment (B operand of S^T = K*Q^T): lane holds Q[qrow][ks*32+lgrp*8..+7]
  bf16x8 qf[2];
  {
    const float* qb = Q + ((size_t)(bh * S_LEN + qrow)) * 64;
#pragma unroll
    for (int ks = 0; ks < 2; ++ks) {
      const float* p = qb + ks * 32 + lgrp * 8;
      qf[ks] = pack8(*(const float4*)p, *(const float4*)(p + 4));
    }
  }

  float m_run = -INFINITY;
  float l_run = 0.f;

  // ===== pass 1: exact row max + denominator; zero-fill interleaved =====
  for (int kt = 0; kt <= qt; ++kt) {
    __syncthreads();
    {
      const float* src = K + ((size_t)(bh * S_LEN + (kt << 6) + sr)) * 64 + sc;
      float4 a0 = ((const float4*)src)[0];
      float4 a1 = ((const float4*)src)[1];
      float4 a2 = ((const float4*)src)[2];
      float4 a3 = ((const float4*)src)[3];
      *(bf16x8*)&ldsK[sr][sc]     = pack8(a0, a1);
      *(bf16x8*)&ldsK[sr][sc + 8] = pack8(a2, a3);
    }

    // ---- interleaved zero stores: slice kt of the masked region ----
    // rows [kt*64/(qt+1), (kt+1)*64/(qt+1)) of block rows, cols kz..2048
    if (kz < S_LEN) {
      const int r0 = (kt * 64) / (qt + 1);
      const int r1 = ((kt + 1) * 64) / (qt + 1);
      for (int r = r0; r < r1; ++r) {
        const size_t base = pOutBase + (size_t)(q0 + r) * S_LEN;
        for (int c = kz + (tid << 2); c < S_LEN; c += 256 * 4) {
          nt_store4(outP + base + c, 0.f, 0.f, 0.f, 0.f);
        }
      }
    }
    __syncthreads();

    f32x4 acc[4];
#pragma unroll
    for (int nt = 0; nt < 4; ++nt) {
      f32x4 a = {0.f, 0.f, 0.f, 0.f};
#pragma unroll
      for (int ks = 0; ks < 2; ++ks) {
        bf16x8 kfrag = *(const bf16x8*)&ldsK[nt * 16 + lrow][ks * 32 + lgrp * 8];
        a = __builtin_amdgcn_mfma_f32_16x16x32_bf16(kfrag, qf[ks], a, 0, 0, 0);
      }
      acc[nt] = a;
    }

    // scale (+ mask only on diagonal tile); lane's 16 regs all belong to qrow
    if (kt == qt) {
#pragma unroll
      for (int nt = 0; nt < 4; ++nt)
#pragma unroll
        for (int rg = 0; rg < 4; ++rg) {
          const int col = (kt << 6) + nt * 16 + (lgrp << 2) + rg;
          acc[nt][rg] = (col > qrow) ? -INFINITY : acc[nt][rg] * SCALE;
        }
    } else {
#pragma unroll
      for (int nt = 0; nt < 4; ++nt)
#pragma unroll
        for (int rg = 0; rg < 4; ++rg) acc[nt][rg] *= SCALE;
    }

    float tm = -INFINITY;
#pragma unroll
    for (int nt = 0; nt < 4; ++nt)
#pragma unroll
      for (int rg = 0; rg < 4; ++rg) tm = fmaxf(tm, acc[nt][rg]);
    tm = fmaxf(tm, __shfl_xor(tm, 16));
    tm = fmaxf(tm, __shfl_xor(tm, 32));
    const float nm = fmaxf(m_run, tm);

    float ps = 0.f;
#pragma unroll
    for (int nt = 0; nt < 4; ++nt)
#pragma unroll
      for (int rg = 0; rg < 4; ++rg) ps += __expf(acc[nt][rg] - nm);
    ps += __shfl_xor(ps, 16);
    ps += __shfl_xor(ps, 32);

    l_run = l_run * __expf(m_run - nm) + ps;
    m_run = nm;
  }

  const float inv_l = 1.f / l_run;

  f32x4 oacc[4];
#pragma unroll
  for (int nt = 0; nt < 4; ++nt) oacc[nt] = (f32x4){0.f, 0.f, 0.f, 0.f};

  const size_t pbase = pOutBase + (size_t)qrow * S_LEN;

  // ================= pass 2: probs, attn store, PV =================
  for (int kt = 0; kt <= qt; ++kt) {
    __syncthreads();
    {
      const float* srcK = K + ((size_t)(bh * S_LEN + (kt << 6) + sr)) * 64 + sc;
      float4 a0 = ((const float4*)srcK)[0];
      float4 a1 = ((const float4*)srcK)[1];
      float4 a2 = ((const float4*)srcK)[2];
      float4 a3 = ((const float4*)srcK)[3];
      *(bf16x8*)&ldsK[sr][sc]     = pack8(a0, a1);
      *(bf16x8*)&ldsK[sr][sc + 8] = pack8(a2, a3);

      const float* srcV = V + ((size_t)(bh * S_LEN + (kt << 6) + sr)) * 64 + sc;
      float4 b0 = ((const float4*)srcV)[0];
      float4 b1 = ((const float4*)srcV)[1];
      float4 b2 = ((const float4*)srcV)[2];
      float4 b3 = ((const float4*)srcV)[3];
      const float vv[16] = {b0.x, b0.y, b0.z, b0.w, b1.x, b1.y, b1.z, b1.w,
                            b2.x, b2.y, b2.z, b2.w, b3.x, b3.y, b3.z, b3.w};
#pragma unroll
      for (int j = 0; j < 16; ++j) ldsV[sc + j][sr] = f2bf(vv[j]);  // transpose
    }
    __syncthreads();

    f32x4 acc[4];
#pragma unroll
    for (int nt = 0; nt < 4; ++nt) {
      f32x4 a = {0.f, 0.f, 0.f, 0.f};
#pragma unroll
      for (int ks = 0; ks < 2; ++ks) {
        bf16x8 kfrag = *(const bf16x8*)&ldsK[nt * 16 + lrow][ks * 32 + lgrp * 8];
        a = __builtin_amdgcn_mfma_f32_16x16x32_bf16(kfrag, qf[ks], a, 0, 0, 0);
      }
      acc[nt] = a;
    }

    if (kt == qt) {
#pragma unroll
      for (int nt = 0; nt < 4; ++nt)
#pragma unroll
        for (int rg = 0; rg < 4; ++rg) {
          const int col = (kt << 6) + nt * 16 + (lgrp << 2) + rg;
          acc[nt][rg] = (col > qrow) ? -INFINITY : acc[nt][rg] * SCALE;
        }
    } else {
#pragma unroll
      for (int nt = 0; nt < 4; ++nt)
#pragma unroll
        for (int rg = 0; rg < 4; ++rg) acc[nt][rg] *= SCALE;
    }

    // probabilities: NT float4 global store + b64 LDS store per nt
#pragma unroll
    for (int nt = 0; nt < 4; ++nt) {
      float p0 = __expf(acc[nt][0] - m_run) * inv_l;
      float p1 = __expf(acc[nt][1] - m_run) * inv_l;
      float p2 = __expf(acc[nt][2] - m_run) * inv_l;
      float p3 = __expf(acc[nt][3] - m_run) * inv_l;
      nt_store4(outP + pbase + (kt << 6) + nt * 16 + (lgrp << 2), p0, p1, p2, p3);
      bf16x4 pb;
      pb[0] = f2bf(p0); pb[1] = f2bf(p1);
      pb[2] = f2bf(p2); pb[3] = f2bf(p3);
      *(bf16x4*)&ldsP[w][lrow][nt * 16 + (lgrp << 2)] = pb;
    }

    // PV: A = own-wave P tile (16q x 64k), B = V^T tile (same-wave LDS
    // write->read; ldsP[w] is wave-private, ordered by lgkmcnt).
#pragma unroll
    for (int nt = 0; nt < 4; ++nt) {
#pragma unroll
      for (int ks = 0; ks < 2; ++ks) {
        bf16x8 pa = *(const bf16x8*)&ldsP[w][lrow][ks * 32 + lgrp * 8];
        bf16x8 vb = *(const bf16x8*)&ldsV[nt * 16 + lrow][ks * 32 + lgrp * 8];
        oacc[nt] = __builtin_amdgcn_mfma_f32_16x16x32_bf16(pa, vb, oacc[nt], 0, 0, 0);
      }
    }
  }

  // ---- write O (fp32): O row = q0+16w+4*lgrp+rg, col d = nt*16+lrow ----
#pragma unroll
  for (int nt = 0; nt < 4; ++nt) {
#pragma unroll
    for (int rg = 0; rg < 4; ++rg) {
      const int rl = (lgrp << 2) + rg;
      const int d  = nt * 16 + lrow;
      __builtin_nontemporal_store(
          oacc[nt][rg],
          outO + ((size_t)(bh * S_LEN + q0 + (w << 4) + rl)) * 64 + d);
    }
  }
}

extern "C" void kernel_launch(void* const* d_in, const int* in_sizes, int n_in,
                              void* d_out, int out_size, void* d_ws, size_t ws_size,
                              hipStream_t stream) {
  const float* Q = (const float*)d_in[0];
  const float* K = (const float*)d_in[1];
  const float* V = (const float*)d_in[2];
  // d_in[3] (mask) is statically causal -> not read.
  float* outO = (float*)d_out;
  float* outP = outO + (size_t)32 * S_LEN * 64;  // after [B,H,S,D] output
  sdpa_kernel<<<dim3(32 * 32), dim3(256), 0, stream>>>(Q, K, V, outO, outP);
}